// Round 1
// baseline (244.373 us; speedup 1.0000x reference)
//
#include <hip/hip_runtime.h>
#include <hip/hip_bf16.h>

#define NB 256
#define NR 100
#define ND 6168
#define DP 6176            // ND padded to multiple of 32
#define NH 128
#define NC 100
#define CP 112             // NC padded to multiple of 16
#define KSTEP 32
#define NSTEP (DP / KSTEP) // 193
#define MT 128             // row tile (NR padded)

typedef __attribute__((ext_vector_type(8))) __bf16 bf16x8;
typedef __attribute__((ext_vector_type(4))) float f32x4;
typedef __attribute__((ext_vector_type(4))) int i32x4;
typedef __attribute__((ext_vector_type(4))) unsigned int u32x4;

// ---------- prep 1: W1 (ND,NH) f32 -> W1T (NH, DP) bf16, zero-padded ----------
__global__ void prep_w1t(const float* __restrict__ W1, __hip_bfloat16* __restrict__ W1T) {
  __shared__ float tile[KSTEP][NH + 1];
  const int d0 = blockIdx.x * KSTEP;
  const int t = threadIdx.x;
#pragma unroll
  for (int p = 0; p < (KSTEP * NH) / 256; ++p) {
    int idx = p * 256 + t;
    int dd = idx >> 7;         // 0..31
    int h  = idx & 127;
    int d  = d0 + dd;
    tile[dd][h] = (d < ND) ? W1[d * NH + h] : 0.f;
  }
  __syncthreads();
#pragma unroll
  for (int p = 0; p < (KSTEP * NH) / 256; ++p) {
    int idx = p * 256 + t;
    int h  = idx >> 5;         // 0..127
    int dd = idx & 31;
    W1T[h * DP + d0 + dd] = __float2bfloat16(tile[dd][h]);
  }
}

// ---------- prep 2: W2 (NH,NC) f32 -> W2T (CP, NH) bf16, zero rows for c>=NC ----------
__global__ void prep_w2t(const float* __restrict__ W2, __hip_bfloat16* __restrict__ W2T) {
  int t = blockIdx.x * 256 + threadIdx.x;
  if (t < CP * NH) {
    int c = t >> 7;
    int h = t & 127;
    float v = (c < NC) ? W2[h * NC + c] : 0.f;
    W2T[t] = __float2bfloat16(v);
  }
}

// ---------- main fused kernel: one block per b ----------
// LDS layout (bytes):
//   phase 1: [0,1024) xbits (194 dwords used)
//            [1024, 11264)  A buf0  (128 rows x 80B stride, 64B data)
//            [11264,21504)  A buf1
//            [21504,31744)  B buf0  (128 rows x 80B)
//            [31744,41984)  B buf1
//   phase 2: [0, 34816)     h_tile  (128 rows x 272B stride, bf16[136])
//            [34816, 38400) partial (8 x 112 f32)
__launch_bounds__(256, 1)
__global__ void fused_main(const int* __restrict__ x,
                           const int* __restrict__ noise,
                           const __hip_bfloat16* __restrict__ W1T,
                           const float* __restrict__ b1,
                           const __hip_bfloat16* __restrict__ W2T,
                           const float* __restrict__ b2,
                           float* __restrict__ out) {
  __shared__ __align__(16) char lds[41984];
  unsigned int* xbits = (unsigned int*)lds;

  const int tid  = threadIdx.x;
  const int lane = tid & 63;
  const int w    = tid >> 6;       // wave 0..3
  const int b    = blockIdx.x;

  const int r    = tid >> 1;            // staging row 0..127 (r for A, h for B)
  const int koff = (tid & 1) * 16;      // element offset within 32-wide K chunk
  const bool rvalid = (r < NR);
  const long nbase = (long)b * NR * ND + (long)r * ND;

  char* const A0 = lds + 1024;
  char* const A1 = A0 + 10240;
  char* const B0 = A1 + 10240;
  char* const B1 = B0 + 10240;

  f32x4 acc[8][2] = {};

  auto LOAD_A = [&](int s, i32x4* areg) {
    const int k0 = s * KSTEP;
#pragma unroll
    for (int j = 0; j < 4; ++j) {
      int c = k0 + koff + j * 4;
      i32x4 v = {0, 0, 0, 0};
      if (rvalid && c < ND) v = *(const i32x4*)(noise + nbase + c);
      areg[j] = v;
    }
  };
  auto LOAD_B = [&](int s, i32x4* breg) {
    const char* src = (const char*)W1T + ((long)r * DP + s * KSTEP) * 2 + (tid & 1) * 32;
    breg[0] = *(const i32x4*)(src);
    breg[1] = *(const i32x4*)(src + 16);
  };
  auto STORE_A = [&](int s, const i32x4* areg, char* Al) {
    unsigned int xw = rvalid ? (xbits[s] >> koff) : 0u;
    unsigned int pk[8];
#pragma unroll
    for (int j = 0; j < 4; ++j) {
#pragma unroll
      for (int e = 0; e < 2; ++e) {
        unsigned v0 = ((unsigned)areg[j][e * 2]     ^ (xw >> (j * 4 + e * 2)))     & 1u;
        unsigned v1 = ((unsigned)areg[j][e * 2 + 1] ^ (xw >> (j * 4 + e * 2 + 1))) & 1u;
        pk[j * 2 + e] = (v0 ? 0x3F80u : 0u) | (v1 ? 0x3F800000u : 0u);
      }
    }
    u32x4* dst = (u32x4*)(Al + r * 80 + koff * 2);
    u32x4 t0 = {pk[0], pk[1], pk[2], pk[3]};
    u32x4 t1 = {pk[4], pk[5], pk[6], pk[7]};
    dst[0] = t0;
    dst[1] = t1;
  };
  auto STORE_B = [&](const i32x4* breg, char* Bl) {
    i32x4* dst = (i32x4*)(Bl + r * 80 + (tid & 1) * 32);
    dst[0] = breg[0];
    dst[1] = breg[1];
  };
  auto COMPUTE = [&](const char* Al, const char* Bl) {
    const int lq = lane >> 4;
    const int lm = lane & 15;
    bf16x8 bf0 = *(const bf16x8*)(Bl + (w * 32 + lm) * 80 + lq * 16);
    bf16x8 bf1 = *(const bf16x8*)(Bl + (w * 32 + 16 + lm) * 80 + lq * 16);
#pragma unroll
    for (int mf = 0; mf < 8; ++mf) {
      bf16x8 af = *(const bf16x8*)(Al + (mf * 16 + lm) * 80 + lq * 16);
      acc[mf][0] = __builtin_amdgcn_mfma_f32_16x16x32_bf16(af, bf0, acc[mf][0], 0, 0, 0);
      acc[mf][1] = __builtin_amdgcn_mfma_f32_16x16x32_bf16(af, bf1, acc[mf][1], 0, 0, 0);
    }
  };

  i32x4 ra0[4], ra1[4], rb0[2], rb1[2];

  // prologue: issue first two tiles' loads, pack x bits, stage tile 0
  LOAD_A(0, ra0); LOAD_B(0, rb0);
  LOAD_A(1, ra1); LOAD_B(1, rb1);
  {
    unsigned long long* xq = (unsigned long long*)lds;
    const int* xb = x + b * ND;
    for (int q = w; q < DP / 64 + 1; q += 4) {   // 97 qwords
      int d = q * 64 + lane;
      int v = (d < ND) ? xb[d] : 0;
      unsigned long long m = __ballot(v != 0);
      if (lane == 0) xq[q] = m;
    }
  }
  __syncthreads();
  STORE_A(0, ra0, A0); STORE_B(rb0, B0);
  __syncthreads();

  for (int s = 0; s < NSTEP; s += 2) {
    if (s + 2 < NSTEP) { LOAD_A(s + 2, ra0); LOAD_B(s + 2, rb0); }
    COMPUTE(A0, B0);
    if (s + 1 < NSTEP) { STORE_A(s + 1, ra1, A1); STORE_B(rb1, B1); }
    __syncthreads();
    if (s + 3 < NSTEP) { LOAD_A(s + 3, ra1); LOAD_B(s + 3, rb1); }
    if (s + 1 < NSTEP) COMPUTE(A1, B1);
    if (s + 2 < NSTEP) { STORE_A(s + 2, ra0, A0); STORE_B(rb0, B0); }
    __syncthreads();
  }

  // ---------------- epilogue ----------------
  __hip_bfloat16* h_tile = (__hip_bfloat16*)lds;       // [128][136] bf16
  float* partial = (float*)(lds + 34816);               // [8][112]
  const int lq = lane >> 4;
  const int lm = lane & 15;

#pragma unroll
  for (int nf = 0; nf < 2; ++nf) {
    int hcol = w * 32 + nf * 16 + lm;
    float bb = b1[hcol];
#pragma unroll
    for (int mf = 0; mf < 8; ++mf) {
#pragma unroll
      for (int rg = 0; rg < 4; ++rg) {
        int m = mf * 16 + lq * 4 + rg;
        float hv = tanhf(acc[mf][nf][rg] + bb);
        h_tile[m * 136 + hcol] = __float2bfloat16(hv);
      }
    }
  }
  __syncthreads();

  // layer 2: rows split by wave: m in [w*32, w*32+32)
  f32x4 acc2[2][7] = {};
#pragma unroll
  for (int ks = 0; ks < 4; ++ks) {
    bf16x8 a2_0 = *(const bf16x8*)((const unsigned short*)h_tile + (w * 32 + lm) * 136 + ks * 32 + lq * 8);
    bf16x8 a2_1 = *(const bf16x8*)((const unsigned short*)h_tile + (w * 32 + 16 + lm) * 136 + ks * 32 + lq * 8);
#pragma unroll
    for (int nf = 0; nf < 7; ++nf) {
      bf16x8 b2f = *(const bf16x8*)((const unsigned short*)W2T + (nf * 16 + lm) * NH + ks * 32 + lq * 8);
      acc2[0][nf] = __builtin_amdgcn_mfma_f32_16x16x32_bf16(a2_0, b2f, acc2[0][nf], 0, 0, 0);
      acc2[1][nf] = __builtin_amdgcn_mfma_f32_16x16x32_bf16(a2_1, b2f, acc2[1][nf], 0, 0, 0);
    }
  }

  // masked column-sum over rows (exclude padded r >= NR), deterministic
#pragma unroll
  for (int mf2 = 0; mf2 < 2; ++mf2) {
    int mbase = w * 32 + mf2 * 16 + lq * 4;
#pragma unroll
    for (int nf = 0; nf < 7; ++nf) {
      float ssum = 0.f;
#pragma unroll
      for (int rg = 0; rg < 4; ++rg) {
        int m = mbase + rg;
        ssum += (m < NR) ? acc2[mf2][nf][rg] : 0.f;
      }
      ssum += __shfl_xor(ssum, 16, 64);
      ssum += __shfl_xor(ssum, 32, 64);
      if (lq == 0) partial[(w * 2 + mf2) * 112 + nf * 16 + lm] = ssum;
    }
  }
  __syncthreads();

  if (tid < NC) {
    float fsum = 0.f;
#pragma unroll
    for (int p = 0; p < 8; ++p) fsum += partial[p * 112 + tid];
    out[b * NC + tid] = fsum * (1.f / NR) + b2[tid];
  }
}

extern "C" void kernel_launch(void* const* d_in, const int* in_sizes, int n_in,
                              void* d_out, int out_size, void* d_ws, size_t ws_size,
                              hipStream_t stream) {
  (void)in_sizes; (void)n_in; (void)out_size; (void)ws_size;
  const int* x     = (const int*)d_in[0];
  const int* noise = (const int*)d_in[1];
  const float* W1  = (const float*)d_in[2];
  const float* b1  = (const float*)d_in[3];
  const float* W2  = (const float*)d_in[4];
  const float* b2  = (const float*)d_in[5];
  float* out = (float*)d_out;

  __hip_bfloat16* W1T = (__hip_bfloat16*)d_ws;
  __hip_bfloat16* W2T = (__hip_bfloat16*)((char*)d_ws + (size_t)NH * DP * 2);

  prep_w1t<<<DP / KSTEP, 256, 0, stream>>>(W1, W1T);
  prep_w2t<<<(CP * NH + 255) / 256, 256, 0, stream>>>(W2, W2T);
  fused_main<<<NB, 256, 0, stream>>>(x, noise, W1T, b1, W2T, b2, out);
}